// Round 16
// baseline (259.943 us; speedup 1.0000x reference)
//
#include <hip/hip_runtime.h>
#include <hip/hip_bf16.h>

// ScaledDotProductAttention: B=2 H=16 S=2048 DK=64, fp32 in, outputs
// (attn_out [B,H,S,DK], weights [B,H,S,S]) concatenated in d_out (fp32).
//
// R16: R13 (195us best) + Ps PAIR-BATCH: Ps = [64][128] bf16 (16KB, 256B
// rows); W flush every 2 tiles writes 512B CONTIGUOUS per row (2 adjacent
// nt dwordx4/lane) instead of 256B/tile. Theory: pass 2 writes 553MB at
// ~2.8TB/s vs fill's 6.7 - DRAM page/burst locality from 256B row visits
// ~2us apart. Cost: LDS 48KB -> 3 blocks/CU (was 4). R15 (zero-barrier
// frag images, 228us) reverted - single-wave L2 loads beat by LDS sharing.
// Rest identical to R13: 256thr QT=64 grid1024, lgkm-only barrier,
// prepacked K/V images, swapped QK^T, fixed m=0, bf16-W from Ps.

namespace {

constexpr int Bc = 2, Hc = 16, Sc = 2048, Dc = 64;
constexpr int QT = 64;             // q rows per block (4 waves x 16)
constexpr int KT = 64;             // kv cols per tile
constexpr int NKV = Sc / KT;       // 32
constexpr int NQB = Sc / QT;       // 32
constexpr int NBH = Bc * Hc;       // 32
constexpr float SCALE2 = 0.125f * 1.44269504088896340736f; // (1/sqrt(64))*log2(e)

// LDS byte offsets (total 48 KB; 3 blocks/CU x 48KB = 144KB <= 160KB)
constexpr int PS_OFF = 0;          // 16 KB bf16[64][128] (aliases Q staging)
constexpr int KS_OFF = 16384;      // 2 x 8 KB, select via (kv&1)*8192
constexpr int VS_OFF = 32768;      // 2 x 8 KB (transposed), same select

// workspace layout
constexpr size_t BITS_BYTES = (size_t)Sc * Sc / 8;            // 512 KB
constexpr size_t IMG_BYTES  = (size_t)NBH * NKV * 8192;       // 8 MB each
constexpr size_t KIMG_OFF   = BITS_BYTES;
constexpr size_t VIMG_OFF   = BITS_BYTES + IMG_BYTES;
constexpr size_t WS_FULL    = BITS_BYTES + 2 * IMG_BYTES;     // ~17 MB

using short8 = __attribute__((ext_vector_type(8))) short;  // 8 bf16 (4 VGPR)
using f32x4  = __attribute__((ext_vector_type(4))) float;  // MFMA acc / stores
using u32x4  = __attribute__((ext_vector_type(4))) unsigned; // 16B copies

// XOR swizzle for 64-col bf16 rows (128B stride): K/V slots (G4).
__device__ __forceinline__ int swz(int row, int bytecol) {
    return row * 128 + (bytecol ^ ((row & 7) << 4));
}
// XOR swizzle for the 128-col bf16 Ps pair buffer (256B rows).
__device__ __forceinline__ int pswz(int row, int bytecol) {
    return row * 256 + (bytecol ^ ((row & 7) << 4));
}

// 2x f32 -> packed bf16 (RNE) in ONE VALU instr (gfx950; no builtin, T12)
__device__ __forceinline__ unsigned cvtpk(float a, float b) {
    unsigned r;
    asm("v_cvt_pk_bf16_f32 %0, %1, %2" : "=v"(r) : "v"(a), "v"(b));
    return r;
}

__device__ __forceinline__ f32x4 mfma16(short8 a, short8 b, f32x4 c) {
    return __builtin_amdgcn_mfma_f32_16x16x32_bf16(a, b, c, 0, 0, 0);
}
__device__ __forceinline__ short8 ldlds(const char* lds, int off, int row,
                                        int bytecol) {
    return *reinterpret_cast<const short8*>(lds + off + swz(row, bytecol));
}

// barrier publishing LDS writes only: NO vmcnt drain (W stores + staging
// loads stay in flight; they are same-thread reg-dep or never-read-in-kernel)
__device__ __forceinline__ void bar_lgkm() {
    __builtin_amdgcn_sched_barrier(0);
    asm volatile("s_waitcnt lgkmcnt(0)" ::: "memory");
    __builtin_amdgcn_s_barrier();
    __builtin_amdgcn_sched_barrier(0);
}
// wave-local LDS fence: order ds_write -> ds_read within this wave
__device__ __forceinline__ void fence_lgkm() {
    __builtin_amdgcn_sched_barrier(0);
    asm volatile("s_waitcnt lgkmcnt(0)" ::: "memory");
    __builtin_amdgcn_sched_barrier(0);
}

// ---- f32 staging helpers (fallback modes + pack_kv pre-kernel) ----
// 64x64 f32 tile handled by a 256-thread group.
__device__ __forceinline__ void ldk_g(const float* __restrict__ src, int tid,
                                      float4 reg[4]) {
    #pragma unroll
    for (int i = 0; i < 4; ++i) {
        int ch = tid + 256 * i;                // 0..1023
        int r = ch >> 4, d0 = (ch & 15) << 2;
        reg[i] = *reinterpret_cast<const float4*>(src + (size_t)r * Dc + d0);
    }
}
__device__ __forceinline__ void stk_g(char* dst, int off, int tid,
                                      const float4 reg[4]) {
    #pragma unroll
    for (int i = 0; i < 4; ++i) {
        int ch = tid + 256 * i;
        int r = ch >> 4, d0 = (ch & 15) << 2;
        uint2 pk; pk.x = cvtpk(reg[i].x, reg[i].y);
        pk.y = cvtpk(reg[i].z, reg[i].w);
        *reinterpret_cast<uint2*>(dst + off + swz(r, d0 * 2)) = pk;
    }
}
__device__ __forceinline__ void ldv_g(const float* __restrict__ src, int tid,
                                      float4 reg[4]) {
    int d0 = (tid & 15) << 2, c0 = (tid >> 4) << 2;
    #pragma unroll
    for (int i = 0; i < 4; ++i)
        reg[i] = *reinterpret_cast<const float4*>(src + (size_t)(c0 + i) * Dc + d0);
}
__device__ __forceinline__ void stv_g(char* dst, int off, int tid,
                                      const float4 reg[4]) {
    int d0 = (tid & 15) << 2, c0 = (tid >> 4) << 2;
    uint2 pk;
    pk.x = cvtpk(reg[0].x, reg[1].x); pk.y = cvtpk(reg[2].x, reg[3].x);
    *reinterpret_cast<uint2*>(dst + off + swz(d0 + 0, c0 * 2)) = pk;
    pk.x = cvtpk(reg[0].y, reg[1].y); pk.y = cvtpk(reg[2].y, reg[3].y);
    *reinterpret_cast<uint2*>(dst + off + swz(d0 + 1, c0 * 2)) = pk;
    pk.x = cvtpk(reg[0].z, reg[1].z); pk.y = cvtpk(reg[2].z, reg[3].z);
    *reinterpret_cast<uint2*>(dst + off + swz(d0 + 2, c0 * 2)) = pk;
    pk.x = cvtpk(reg[0].w, reg[1].w); pk.y = cvtpk(reg[2].w, reg[3].w);
    *reinterpret_cast<uint2*>(dst + off + swz(d0 + 3, c0 * 2)) = pk;
}

// ---- pre-kernels ----
__global__ __launch_bounds__(256) void pack_mask(
    const int* __restrict__ Mg, unsigned long long* __restrict__ bits)
{
    int tg = blockIdx.x * 256 + threadIdx.x;        // over S*S
    int v = Mg[tg];
    unsigned long long b = __ballot(v != 0);
    if ((threadIdx.x & 63) == 0) bits[tg >> 6] = b;
}

// one block per (bh, kv): emit the exact 8KB swizzled-bf16 LDS image of the
// K tile and the TRANSPOSED V tile.
__global__ __launch_bounds__(256) void pack_kv(
    const float* __restrict__ Kg, const float* __restrict__ Vg,
    char* __restrict__ kimg, char* __restrict__ vimg)
{
    const int b = blockIdx.x;                   // 0..1023
    const int bh = b >> 5, kv = b & 31;
    const int t = threadIdx.x;
    const size_t off = (size_t)bh * Sc * Dc + (size_t)kv * KT * Dc;
    float4 kreg[4];
    ldk_g(Kg + off, t, kreg);
    stk_g(kimg + (size_t)b * 8192, 0, t, kreg);
    float4 vreg[4];
    ldv_g(Vg + off, t, vreg);
    stv_g(vimg + (size_t)b * 8192, 0, t, vreg);
}

// MODE: 0 = raw mask + f32 staging; 1 = bit mask + f32 staging;
//       2 = bit mask + prepacked bf16 K/V images
template <int MODE>
__global__ __launch_bounds__(256, 3)
void attn_main(const float* __restrict__ Qg, const float* __restrict__ Kg,
               const float* __restrict__ Vg, const int* __restrict__ Mg,
               const unsigned* __restrict__ mbits,
               const char* __restrict__ kimg, const char* __restrict__ vimg,
               float* __restrict__ Og, float* __restrict__ Wg)
{
    constexpr bool USE_BITS = (MODE >= 1);
    __shared__ char lds_s[49152];
    char* lds = lds_s;   // decay once; all accesses via integer offsets

    // XCD-grouped mapping: 4 bh per XCD -> K/V images stay L2-resident.
    const int bid = blockIdx.x;                 // 0..1023
    const int xcd = bid & 7, idx = bid >> 3;    // idx 0..127
    const int bh  = xcd * 4 + (idx & 3);        // 0..31
    const int qb  = idx >> 2;                   // 0..31

    const int t    = threadIdx.x;               // 0..255
    const int lane = t & 63;
    const int w    = t >> 6;                    // wave 0..3
    const int l15  = lane & 15, hi4 = lane >> 4;
    const int qw   = 16 * w;                    // wave's first q row in block

    const size_t bh_off = (size_t)bh * Sc * Dc;
    const float* Qb = Qg + bh_off + (size_t)qb * QT * Dc;
    const float* Kb = Kg + bh_off;
    const float* Vb = Vg + bh_off;
    float* Ob = Og + bh_off + (size_t)qb * QT * Dc;
    float* Wb = Wg + (size_t)bh * Sc * Sc + (size_t)qb * QT * Sc;

    // the single q row this thread owns in S^T layout
    const int ql0 = qw + l15;          // block-local (0..63)
    const int qg0 = qb * QT + ql0;     // global row within (b,h)

    // ---- stage Q (scaled, into Ps area) + K tile 0; one barrier ----
    {
        float4 qreg[4];
        ldk_g(Qb, t, qreg);            // Q tile is 64x64, same shape as K
        #pragma unroll
        for (int i = 0; i < 4; ++i) {
            int ch = t + 256 * i;
            int r = ch >> 4, d0 = (ch & 15) << 2;
            uint2 pk;
            pk.x = cvtpk(qreg[i].x * SCALE2, qreg[i].y * SCALE2);
            pk.y = cvtpk(qreg[i].z * SCALE2, qreg[i].w * SCALE2);
            *reinterpret_cast<uint2*>(lds + PS_OFF + pswz(r, d0 * 2)) = pk;
        }
    }
    if constexpr (MODE == 2) {
        const char* src = kimg + (size_t)(bh * 32) * 8192 + t * 16;
        *reinterpret_cast<u32x4*>(lds + KS_OFF + t * 16) =
            *reinterpret_cast<const u32x4*>(src);
        *reinterpret_cast<u32x4*>(lds + KS_OFF + t * 16 + 4096) =
            *reinterpret_cast<const u32x4*>(src + 4096);
    } else {
        float4 kreg[4];
        ldk_g(Kb, t, kreg);
        stk_g(lds, KS_OFF, t, kreg);
    }
    bar_lgkm();

    // ---- hoist Q fragments to registers (frees Ps area for pass 2) ----
    short8 qf[2];
    #pragma unroll
    for (int kk = 0; kk < 2; ++kk)
        qf[kk] = *reinterpret_cast<const short8*>(
            lds + PS_OFF + pswz(qw + l15, kk * 64 + hi4 * 16));

    float lsum = 0.f;

    // ================= pass 1: row sums only (fixed m = 0) =================
    for (int kv = 0; kv < NKV; ++kv) {
        const int nx = (kv + 1) & (NKV - 1);    // wraps to 0 -> preload pass 2
        const int cko = KS_OFF + (kv & 1) * 8192;
        float4 sreg[4], vreg[4];
        u32x4 s0, s1, v0, v1;
        if constexpr (MODE == 2) {
            const char* src = kimg + (size_t)(bh * 32 + nx) * 8192 + t * 16;
            s0 = *reinterpret_cast<const u32x4*>(src);
            s1 = *reinterpret_cast<const u32x4*>(src + 4096);
            if (kv == NKV - 1) {
                const char* vs = vimg + (size_t)(bh * 32) * 8192 + t * 16;
                v0 = *reinterpret_cast<const u32x4*>(vs);
                v1 = *reinterpret_cast<const u32x4*>(vs + 4096);
            }
        } else {
            ldk_g(Kb + (size_t)nx * KT * Dc, t, sreg);
            if (kv == NKV - 1) ldv_g(Vb, t, vreg);
        }

        uint2 mb0;
        if (USE_BITS)
            mb0 = *reinterpret_cast<const uint2*>(mbits + (size_t)qg0 * 64 + kv * 2);

        // swapped QK^T: sc[ct] = S^T block; lane holds
        // k = kv*64 + ct*16 + hi4*4 + r,  q = qw + l15
        f32x4 sc[4];
        #pragma unroll
        for (int ct = 0; ct < 4; ++ct) sc[ct] = f32x4{0.f, 0.f, 0.f, 0.f};
        #pragma unroll
        for (int kk = 0; kk < 2; ++kk) {
            int bc = kk * 64 + hi4 * 16;
            #pragma unroll
            for (int ct = 0; ct < 4; ++ct) {
                short8 kf = ldlds(lds, cko, ct * 16 + l15, bc);
                sc[ct] = mfma16(kf, qf[kk], sc[ct]);
            }
        }

        {
            float acc = 0.f;
            #pragma unroll
            for (int ct = 0; ct < 4; ++ct) {
                unsigned word = (ct >= 2) ? mb0.y : mb0.x;
                #pragma unroll
                for (int r = 0; r < 4; ++r) {
                    bool keep;
                    if (USE_BITS)
                        keep = (word >> ((ct & 1) * 16 + hi4 * 4 + r)) & 1;
                    else
                        keep = Mg[(size_t)qg0 * Sc + kv * KT + ct * 16 + hi4 * 4 + r] != 0;
                    acc += keep ? exp2f(sc[ct][r]) : 0.0f;
                }
            }
            lsum += acc;
        }

        // write-late: next K tile (and V tile 0 at the wrap)
        if constexpr (MODE == 2) {
            char* d = lds + KS_OFF + (nx & 1) * 8192 + t * 16;
            *reinterpret_cast<u32x4*>(d) = s0;
            *reinterpret_cast<u32x4*>(d + 4096) = s1;
            if (kv == NKV - 1) {
                char* dv = lds + VS_OFF + t * 16;
                *reinterpret_cast<u32x4*>(dv) = v0;
                *reinterpret_cast<u32x4*>(dv + 4096) = v1;
            }
        } else {
            stk_g(lds, KS_OFF + (nx & 1) * 8192, t, sreg);
            if (kv == NKV - 1) stv_g(lds, VS_OFF, t, vreg);
        }
        bar_lgkm();
    }

    // cross-lane merge over the 4 hi4 groups (each holds a k-quarter)
    float rls;
    {
        float s = lsum;
        s += __shfl_xor(s, 16);
        s += __shfl_xor(s, 32);
        rls = 1.0f / s;
    }

    // ============ pass 2: W write (Ps pair, 512B bursts) + PV =============
    f32x4 oa[4];
    #pragma unroll
    for (int dt = 0; dt < 4; ++dt) oa[dt] = f32x4{0.f, 0.f, 0.f, 0.f};

    for (int kv = 0; kv < NKV; ++kv) {
        const bool pf = (kv + 1) < NKV;
        const int cko = KS_OFF + (kv & 1) * 8192;
        const int cvo = VS_OFF + (kv & 1) * 8192;
        const int psj = (kv & 1) * 128;         // Ps pair half (byte offset)
        float4 sreg[4], vreg[4];
        u32x4 s0, s1, s2, s3;
        if (pf) {
            if constexpr (MODE == 2) {
                // waves 0-1 fetch K-next, waves 2-3 fetch V-next (4x16B each)
                const int ht = t & 127;
                const char* src = (t < 128)
                    ? kimg + (size_t)(bh * 32 + kv + 1) * 8192 + ht * 16
                    : vimg + (size_t)(bh * 32 + kv + 1) * 8192 + ht * 16;
                s0 = *reinterpret_cast<const u32x4*>(src);
                s1 = *reinterpret_cast<const u32x4*>(src + 2048);
                s2 = *reinterpret_cast<const u32x4*>(src + 4096);
                s3 = *reinterpret_cast<const u32x4*>(src + 6144);
            } else {
                ldk_g(Kb + (size_t)(kv + 1) * KT * Dc, t, sreg);
                ldv_g(Vb + (size_t)(kv + 1) * KT * Dc, t, vreg);
            }
        }

        uint2 mb0;
        if (USE_BITS)
            mb0 = *reinterpret_cast<const uint2*>(mbits + (size_t)qg0 * 64 + kv * 2);

        // swapped QK^T (recompute)
        f32x4 sc[4];
        #pragma unroll
        for (int ct = 0; ct < 4; ++ct) sc[ct] = f32x4{0.f, 0.f, 0.f, 0.f};
        #pragma unroll
        for (int kk = 0; kk < 2; ++kk) {
            int bc = kk * 64 + hi4 * 16;
            #pragma unroll
            for (int ct = 0; ct < 4; ++ct) {
                short8 kf = ldlds(lds, cko, ct * 16 + l15, bc);
                sc[ct] = mfma16(kf, qf[kk], sc[ct]);
            }
        }

        // weights -> Ps pair half (bf16; serves PV A-operand AND W flush)
        #pragma unroll
        for (int ct = 0; ct < 4; ++ct) {
            unsigned word = (ct >= 2) ? mb0.y : mb0.x;
            float p[4];
            #pragma unroll
            for (int r = 0; r < 4; ++r) {
                bool keep;
                if (USE_BITS)
                    keep = (word >> ((ct & 1) * 16 + hi4 * 4 + r)) & 1;
                else
                    keep = Mg[(size_t)qg0 * Sc + kv * KT + ct * 16 + hi4 * 4 + r] != 0;
                p[r] = keep ? exp2f(sc[ct][r]) * rls : 0.0f;
            }
            uint2 pp; pp.x = cvtpk(p[0], p[1]); pp.y = cvtpk(p[2], p[3]);
            *reinterpret_cast<uint2*>(
                lds + PS_OFF + pswz(ql0, psj + ct * 32 + hi4 * 8)) = pp;
        }
        // wave-local fence: Ps writes -> reads below (same wave's rows)
        fence_lgkm();

        // PV: oa += P(bf16) * V^T(bf16)
        #pragma unroll
        for (int kk = 0; kk < 2; ++kk) {
            int bc = kk * 64 + hi4 * 16;       // k = kk*32 + hi4*8 + e
            short8 a0 = *reinterpret_cast<const short8*>(
                lds + PS_OFF + pswz(qw + l15, psj + bc));
            #pragma unroll
            for (int dt = 0; dt < 4; ++dt) {
                short8 b = ldlds(lds, cvo, dt * 16 + l15, bc);
                oa[dt] = mfma16(a0, b, oa[dt]);
            }
        }

        // W flush every 2 tiles: 512B CONTIGUOUS per row visit. Lane covers
        // cols l15*8..+7 of the 128-col pair (byte = l15*16 in Ps row);
        // 2 adjacent nt dwordx4 per lane per row.
        if (kv & 1) {
            #pragma unroll
            for (int j = 0; j < 4; ++j) {
                int row = qw + j * 4 + hi4;
                u32x4 pw = *reinterpret_cast<const u32x4*>(
                    lds + PS_OFF + pswz(row, l15 * 16));
                f32x4 w0, w1;
                w0[0] = __uint_as_float(pw[0] << 16);
                w0[1] = __uint_as_float(pw[0] & 0xffff0000u);
                w0[2] = __uint_as_float(pw[1] << 16);
                w0[3] = __uint_as_float(pw[1] & 0xffff0000u);
                w1[0] = __uint_as_float(pw[2] << 16);
                w1[1] = __uint_as_float(pw[2] & 0xffff0000u);
                w1[2] = __uint_as_float(pw[3] << 16);
                w1[3] = __uint_as_float(pw[3] & 0xffff0000u);
                float* wr = Wb + (size_t)row * Sc + (kv - 1) * KT + l15 * 8;
                __builtin_nontemporal_store(w0, reinterpret_cast<f32x4*>(wr));
                __builtin_nontemporal_store(w1, reinterpret_cast<f32x4*>(wr + 4));
            }
        }

        // write-late staging for next tile, then the LDS-only barrier
        if (pf) {
            if constexpr (MODE == 2) {
                const int ht = t & 127;
                char* d = (t < 128)
                    ? lds + KS_OFF + ((kv + 1) & 1) * 8192 + ht * 16
                    : lds + VS_OFF + ((kv + 1) & 1) * 8192 + ht * 16;
                *reinterpret_cast<u32x4*>(d) = s0;
                *reinterpret_cast<u32x4*>(d + 2048) = s1;
                *reinterpret_cast<u32x4*>(d + 4096) = s2;
                *reinterpret_cast<u32x4*>(d + 6144) = s3;
            } else {
                stk_g(lds, KS_OFF + ((kv + 1) & 1) * 8192, t, sreg);
                stv_g(lds, VS_OFF + ((kv + 1) & 1) * 8192, t, vreg);
            }
        }
        bar_lgkm();
    }

    // epilogue: store O (nontemporal, coalesced; once per kernel)
    #pragma unroll
    for (int dt = 0; dt < 4; ++dt)
        #pragma unroll
        for (int r = 0; r < 4; ++r) {
            int ql = qw + hi4 * 4 + r;
            __builtin_nontemporal_store(
                oa[dt][r], Ob + (size_t)ql * Dc + dt * 16 + l15);
        }
}

} // namespace

extern "C" void kernel_launch(void* const* d_in, const int* in_sizes, int n_in,
                              void* d_out, int out_size, void* d_ws, size_t ws_size,
                              hipStream_t stream) {
    const float* Qg = (const float*)d_in[0];
    const float* Kg = (const float*)d_in[1];
    const float* Vg = (const float*)d_in[2];
    const int*   Mg = (const int*)d_in[3];
    float* out_o = (float*)d_out;
    float* out_w = out_o + (size_t)Bc * Hc * Sc * Dc;   // weights after output

    char* ws = (char*)d_ws;
    dim3 grid(NQB * NBH), blk(256);

    if (d_ws != nullptr && ws_size >= WS_FULL) {
        unsigned long long* bits = (unsigned long long*)ws;
        char* kimg = ws + KIMG_OFF;
        char* vimg = ws + VIMG_OFF;
        pack_mask<<<(Sc * Sc) / 256, 256, 0, stream>>>(Mg, bits);
        pack_kv<<<NBH * NKV, 256, 0, stream>>>(Kg, Vg, kimg, vimg);
        attn_main<2><<<grid, blk, 0, stream>>>(
            Qg, Kg, Vg, Mg, (const unsigned*)bits, kimg, vimg, out_o, out_w);
    } else if (d_ws != nullptr && ws_size >= BITS_BYTES) {
        pack_mask<<<(Sc * Sc) / 256, 256, 0, stream>>>(
            Mg, (unsigned long long*)ws);
        attn_main<1><<<grid, blk, 0, stream>>>(
            Qg, Kg, Vg, Mg, (const unsigned*)ws, nullptr, nullptr, out_o, out_w);
    } else {
        attn_main<0><<<grid, blk, 0, stream>>>(
            Qg, Kg, Vg, Mg, nullptr, nullptr, nullptr, out_o, out_w);
    }
}

// Round 17
// 193.666 us; speedup vs baseline: 1.3422x; 1.3422x over previous
//
#include <hip/hip_runtime.h>
#include <hip/hip_bf16.h>

// ScaledDotProductAttention: B=2 H=16 S=2048 DK=64, fp32 in, outputs
// (attn_out [B,H,S,DK], weights [B,H,S,S]) concatenated in d_out (fp32).
//
// R17 = R13 verbatim (195.0us best). Ledger: wins = W-store segment
// structure (R10: transposed flush, 4 full 256B line-aligned row segments
// per store instr), nt on full lines (R12), cvt_pk conversion (R7),
// 4 independent blocks/CU (R13). Falsified: reg write-batching (R9),
// barrier halving (R14 null), zero-barrier frag images (R15), 512B
// pair-burst at 3 blk/CU (R16). If this reproduces ~195us -> roofline.

namespace {

constexpr int Bc = 2, Hc = 16, Sc = 2048, Dc = 64;
constexpr int QT = 64;             // q rows per block (4 waves x 16)
constexpr int KT = 64;             // kv cols per tile
constexpr int NKV = Sc / KT;       // 32
constexpr int NQB = Sc / QT;       // 32
constexpr int NBH = Bc * Hc;       // 32
constexpr float SCALE2 = 0.125f * 1.44269504088896340736f; // (1/sqrt(64))*log2(e)

// LDS byte offsets (total 40 KB; 4 blocks/CU x 40KB = 160KB = full LDS)
constexpr int PS_OFF = 0;          //  8 KB bf16[64][64] (aliases Q staging)
constexpr int KS_OFF = 8192;       // 2 x 8 KB, select via (kv&1)*8192
constexpr int VS_OFF = 24576;      // 2 x 8 KB (transposed), same select

// workspace layout
constexpr size_t BITS_BYTES = (size_t)Sc * Sc / 8;            // 512 KB
constexpr size_t IMG_BYTES  = (size_t)NBH * NKV * 8192;       // 8 MB each
constexpr size_t KIMG_OFF   = BITS_BYTES;
constexpr size_t VIMG_OFF   = BITS_BYTES + IMG_BYTES;
constexpr size_t WS_FULL    = BITS_BYTES + 2 * IMG_BYTES;     // ~17 MB

using short8 = __attribute__((ext_vector_type(8))) short;  // 8 bf16 (4 VGPR)
using f32x4  = __attribute__((ext_vector_type(4))) float;  // MFMA acc / stores
using u32x4  = __attribute__((ext_vector_type(4))) unsigned; // 16B copies

// XOR swizzle for 64-col bf16 rows (128B stride): bank-conflict fix (G4).
__device__ __forceinline__ int swz(int row, int bytecol) {
    return row * 128 + (bytecol ^ ((row & 7) << 4));
}

// 2x f32 -> packed bf16 (RNE) in ONE VALU instr (gfx950; no builtin, T12)
__device__ __forceinline__ unsigned cvtpk(float a, float b) {
    unsigned r;
    asm("v_cvt_pk_bf16_f32 %0, %1, %2" : "=v"(r) : "v"(a), "v"(b));
    return r;
}

__device__ __forceinline__ f32x4 mfma16(short8 a, short8 b, f32x4 c) {
    return __builtin_amdgcn_mfma_f32_16x16x32_bf16(a, b, c, 0, 0, 0);
}
__device__ __forceinline__ short8 ldlds(const char* lds, int off, int row,
                                        int bytecol) {
    return *reinterpret_cast<const short8*>(lds + off + swz(row, bytecol));
}

// barrier publishing LDS writes only: NO vmcnt drain (W stores + staging
// loads stay in flight; they are same-thread reg-dep or never-read-in-kernel)
__device__ __forceinline__ void bar_lgkm() {
    __builtin_amdgcn_sched_barrier(0);
    asm volatile("s_waitcnt lgkmcnt(0)" ::: "memory");
    __builtin_amdgcn_s_barrier();
    __builtin_amdgcn_sched_barrier(0);
}
// wave-local LDS fence: order ds_write -> ds_read within this wave
__device__ __forceinline__ void fence_lgkm() {
    __builtin_amdgcn_sched_barrier(0);
    asm volatile("s_waitcnt lgkmcnt(0)" ::: "memory");
    __builtin_amdgcn_sched_barrier(0);
}

// ---- f32 staging helpers (fallback modes + pack_kv pre-kernel) ----
// 64x64 f32 tile handled by a 256-thread group.
__device__ __forceinline__ void ldk_g(const float* __restrict__ src, int tid,
                                      float4 reg[4]) {
    #pragma unroll
    for (int i = 0; i < 4; ++i) {
        int ch = tid + 256 * i;                // 0..1023
        int r = ch >> 4, d0 = (ch & 15) << 2;
        reg[i] = *reinterpret_cast<const float4*>(src + (size_t)r * Dc + d0);
    }
}
__device__ __forceinline__ void stk_g(char* dst, int off, int tid,
                                      const float4 reg[4]) {
    #pragma unroll
    for (int i = 0; i < 4; ++i) {
        int ch = tid + 256 * i;
        int r = ch >> 4, d0 = (ch & 15) << 2;
        uint2 pk; pk.x = cvtpk(reg[i].x, reg[i].y);
        pk.y = cvtpk(reg[i].z, reg[i].w);
        *reinterpret_cast<uint2*>(dst + off + swz(r, d0 * 2)) = pk;
    }
}
__device__ __forceinline__ void ldv_g(const float* __restrict__ src, int tid,
                                      float4 reg[4]) {
    int d0 = (tid & 15) << 2, c0 = (tid >> 4) << 2;
    #pragma unroll
    for (int i = 0; i < 4; ++i)
        reg[i] = *reinterpret_cast<const float4*>(src + (size_t)(c0 + i) * Dc + d0);
}
__device__ __forceinline__ void stv_g(char* dst, int off, int tid,
                                      const float4 reg[4]) {
    int d0 = (tid & 15) << 2, c0 = (tid >> 4) << 2;
    uint2 pk;
    pk.x = cvtpk(reg[0].x, reg[1].x); pk.y = cvtpk(reg[2].x, reg[3].x);
    *reinterpret_cast<uint2*>(dst + off + swz(d0 + 0, c0 * 2)) = pk;
    pk.x = cvtpk(reg[0].y, reg[1].y); pk.y = cvtpk(reg[2].y, reg[3].y);
    *reinterpret_cast<uint2*>(dst + off + swz(d0 + 1, c0 * 2)) = pk;
    pk.x = cvtpk(reg[0].z, reg[1].z); pk.y = cvtpk(reg[2].z, reg[3].z);
    *reinterpret_cast<uint2*>(dst + off + swz(d0 + 2, c0 * 2)) = pk;
    pk.x = cvtpk(reg[0].w, reg[1].w); pk.y = cvtpk(reg[2].w, reg[3].w);
    *reinterpret_cast<uint2*>(dst + off + swz(d0 + 3, c0 * 2)) = pk;
}

// ---- pre-kernels ----
__global__ __launch_bounds__(256) void pack_mask(
    const int* __restrict__ Mg, unsigned long long* __restrict__ bits)
{
    int tg = blockIdx.x * 256 + threadIdx.x;        // over S*S
    int v = Mg[tg];
    unsigned long long b = __ballot(v != 0);
    if ((threadIdx.x & 63) == 0) bits[tg >> 6] = b;
}

// one block per (bh, kv): emit the exact 8KB swizzled-bf16 LDS image of the
// K tile and the TRANSPOSED V tile.
__global__ __launch_bounds__(256) void pack_kv(
    const float* __restrict__ Kg, const float* __restrict__ Vg,
    char* __restrict__ kimg, char* __restrict__ vimg)
{
    const int b = blockIdx.x;                   // 0..1023
    const int bh = b >> 5, kv = b & 31;
    const int t = threadIdx.x;
    const size_t off = (size_t)bh * Sc * Dc + (size_t)kv * KT * Dc;
    float4 kreg[4];
    ldk_g(Kg + off, t, kreg);
    stk_g(kimg + (size_t)b * 8192, 0, t, kreg);
    float4 vreg[4];
    ldv_g(Vg + off, t, vreg);
    stv_g(vimg + (size_t)b * 8192, 0, t, vreg);
}

// MODE: 0 = raw mask + f32 staging; 1 = bit mask + f32 staging;
//       2 = bit mask + prepacked bf16 K/V images
template <int MODE>
__global__ __launch_bounds__(256, 4)
void attn_main(const float* __restrict__ Qg, const float* __restrict__ Kg,
               const float* __restrict__ Vg, const int* __restrict__ Mg,
               const unsigned* __restrict__ mbits,
               const char* __restrict__ kimg, const char* __restrict__ vimg,
               float* __restrict__ Og, float* __restrict__ Wg)
{
    constexpr bool USE_BITS = (MODE >= 1);
    __shared__ char lds_s[40960];
    char* lds = lds_s;   // decay once; all accesses via integer offsets

    // XCD-grouped mapping: 4 bh per XCD -> K/V images stay L2-resident.
    const int bid = blockIdx.x;                 // 0..1023
    const int xcd = bid & 7, idx = bid >> 3;    // idx 0..127
    const int bh  = xcd * 4 + (idx & 3);        // 0..31
    const int qb  = idx >> 2;                   // 0..31

    const int t    = threadIdx.x;               // 0..255
    const int lane = t & 63;
    const int w    = t >> 6;                    // wave 0..3
    const int l15  = lane & 15, hi4 = lane >> 4;
    const int qw   = 16 * w;                    // wave's first q row in block

    const size_t bh_off = (size_t)bh * Sc * Dc;
    const float* Qb = Qg + bh_off + (size_t)qb * QT * Dc;
    const float* Kb = Kg + bh_off;
    const float* Vb = Vg + bh_off;
    float* Ob = Og + bh_off + (size_t)qb * QT * Dc;
    float* Wb = Wg + (size_t)bh * Sc * Sc + (size_t)qb * QT * Sc;

    // the single q row this thread owns in S^T layout
    const int ql0 = qw + l15;          // block-local (0..63)
    const int qg0 = qb * QT + ql0;     // global row within (b,h)

    // ---- stage Q (scaled, into Ps area) + K tile 0; one barrier ----
    {
        float4 qreg[4];
        ldk_g(Qb, t, qreg);            // Q tile is 64x64, same shape as K
        #pragma unroll
        for (int i = 0; i < 4; ++i) {
            int ch = t + 256 * i;
            int r = ch >> 4, d0 = (ch & 15) << 2;
            uint2 pk;
            pk.x = cvtpk(qreg[i].x * SCALE2, qreg[i].y * SCALE2);
            pk.y = cvtpk(qreg[i].z * SCALE2, qreg[i].w * SCALE2);
            *reinterpret_cast<uint2*>(lds + PS_OFF + swz(r, d0 * 2)) = pk;
        }
    }
    if constexpr (MODE == 2) {
        const char* src = kimg + (size_t)(bh * 32) * 8192 + t * 16;
        *reinterpret_cast<u32x4*>(lds + KS_OFF + t * 16) =
            *reinterpret_cast<const u32x4*>(src);
        *reinterpret_cast<u32x4*>(lds + KS_OFF + t * 16 + 4096) =
            *reinterpret_cast<const u32x4*>(src + 4096);
    } else {
        float4 kreg[4];
        ldk_g(Kb, t, kreg);
        stk_g(lds, KS_OFF, t, kreg);
    }
    bar_lgkm();

    // ---- hoist Q fragments to registers (frees Ps area for pass 2) ----
    short8 qf[2];
    #pragma unroll
    for (int kk = 0; kk < 2; ++kk)
        qf[kk] = ldlds(lds, PS_OFF, qw + l15, kk * 64 + hi4 * 16);

    float lsum = 0.f;

    // ================= pass 1: row sums only (fixed m = 0) =================
    for (int kv = 0; kv < NKV; ++kv) {
        const int nx = (kv + 1) & (NKV - 1);    // wraps to 0 -> preload pass 2
        const int cko = KS_OFF + (kv & 1) * 8192;
        float4 sreg[4], vreg[4];
        u32x4 s0, s1, v0, v1;
        if constexpr (MODE == 2) {
            const char* src = kimg + (size_t)(bh * 32 + nx) * 8192 + t * 16;
            s0 = *reinterpret_cast<const u32x4*>(src);
            s1 = *reinterpret_cast<const u32x4*>(src + 4096);
            if (kv == NKV - 1) {
                const char* vs = vimg + (size_t)(bh * 32) * 8192 + t * 16;
                v0 = *reinterpret_cast<const u32x4*>(vs);
                v1 = *reinterpret_cast<const u32x4*>(vs + 4096);
            }
        } else {
            ldk_g(Kb + (size_t)nx * KT * Dc, t, sreg);
            if (kv == NKV - 1) ldv_g(Vb, t, vreg);
        }

        uint2 mb0;
        if (USE_BITS)
            mb0 = *reinterpret_cast<const uint2*>(mbits + (size_t)qg0 * 64 + kv * 2);

        // swapped QK^T: sc[ct] = S^T block; lane holds
        // k = kv*64 + ct*16 + hi4*4 + r,  q = qw + l15
        f32x4 sc[4];
        #pragma unroll
        for (int ct = 0; ct < 4; ++ct) sc[ct] = f32x4{0.f, 0.f, 0.f, 0.f};
        #pragma unroll
        for (int kk = 0; kk < 2; ++kk) {
            int bc = kk * 64 + hi4 * 16;
            #pragma unroll
            for (int ct = 0; ct < 4; ++ct) {
                short8 kf = ldlds(lds, cko, ct * 16 + l15, bc);
                sc[ct] = mfma16(kf, qf[kk], sc[ct]);
            }
        }

        {
            float acc = 0.f;
            #pragma unroll
            for (int ct = 0; ct < 4; ++ct) {
                unsigned word = (ct >= 2) ? mb0.y : mb0.x;
                #pragma unroll
                for (int r = 0; r < 4; ++r) {
                    bool keep;
                    if (USE_BITS)
                        keep = (word >> ((ct & 1) * 16 + hi4 * 4 + r)) & 1;
                    else
                        keep = Mg[(size_t)qg0 * Sc + kv * KT + ct * 16 + hi4 * 4 + r] != 0;
                    acc += keep ? exp2f(sc[ct][r]) : 0.0f;
                }
            }
            lsum += acc;
        }

        // write-late: next K tile (and V tile 0 at the wrap)
        if constexpr (MODE == 2) {
            char* d = lds + KS_OFF + (nx & 1) * 8192 + t * 16;
            *reinterpret_cast<u32x4*>(d) = s0;
            *reinterpret_cast<u32x4*>(d + 4096) = s1;
            if (kv == NKV - 1) {
                char* dv = lds + VS_OFF + t * 16;
                *reinterpret_cast<u32x4*>(dv) = v0;
                *reinterpret_cast<u32x4*>(dv + 4096) = v1;
            }
        } else {
            stk_g(lds, KS_OFF + (nx & 1) * 8192, t, sreg);
            if (kv == NKV - 1) stv_g(lds, VS_OFF, t, vreg);
        }
        bar_lgkm();
    }

    // cross-lane merge over the 4 hi4 groups (each holds a k-quarter)
    float rls;
    {
        float s = lsum;
        s += __shfl_xor(s, 16);
        s += __shfl_xor(s, 32);
        rls = 1.0f / s;
    }

    // ================= pass 2: W write (via Ps, transposed) + PV ===========
    f32x4 oa[4];
    #pragma unroll
    for (int dt = 0; dt < 4; ++dt) oa[dt] = f32x4{0.f, 0.f, 0.f, 0.f};

    for (int kv = 0; kv < NKV; ++kv) {
        const bool pf = (kv + 1) < NKV;
        const int cko = KS_OFF + (kv & 1) * 8192;
        const int cvo = VS_OFF + (kv & 1) * 8192;
        float4 sreg[4], vreg[4];
        u32x4 s0, s1, s2, s3;
        if (pf) {
            if constexpr (MODE == 2) {
                // waves 0-1 fetch K-next, waves 2-3 fetch V-next (4x16B each)
                const int ht = t & 127;
                const char* src = (t < 128)
                    ? kimg + (size_t)(bh * 32 + kv + 1) * 8192 + ht * 16
                    : vimg + (size_t)(bh * 32 + kv + 1) * 8192 + ht * 16;
                s0 = *reinterpret_cast<const u32x4*>(src);
                s1 = *reinterpret_cast<const u32x4*>(src + 2048);
                s2 = *reinterpret_cast<const u32x4*>(src + 4096);
                s3 = *reinterpret_cast<const u32x4*>(src + 6144);
            } else {
                ldk_g(Kb + (size_t)(kv + 1) * KT * Dc, t, sreg);
                ldv_g(Vb + (size_t)(kv + 1) * KT * Dc, t, vreg);
            }
        }

        uint2 mb0;
        if (USE_BITS)
            mb0 = *reinterpret_cast<const uint2*>(mbits + (size_t)qg0 * 64 + kv * 2);

        // swapped QK^T (recompute)
        f32x4 sc[4];
        #pragma unroll
        for (int ct = 0; ct < 4; ++ct) sc[ct] = f32x4{0.f, 0.f, 0.f, 0.f};
        #pragma unroll
        for (int kk = 0; kk < 2; ++kk) {
            int bc = kk * 64 + hi4 * 16;
            #pragma unroll
            for (int ct = 0; ct < 4; ++ct) {
                short8 kf = ldlds(lds, cko, ct * 16 + l15, bc);
                sc[ct] = mfma16(kf, qf[kk], sc[ct]);
            }
        }

        // weights -> Ps only (bf16; serves the PV A-operand AND the
        // transposed W flush below)
        #pragma unroll
        for (int ct = 0; ct < 4; ++ct) {
            unsigned word = (ct >= 2) ? mb0.y : mb0.x;
            float p[4];
            #pragma unroll
            for (int r = 0; r < 4; ++r) {
                bool keep;
                if (USE_BITS)
                    keep = (word >> ((ct & 1) * 16 + hi4 * 4 + r)) & 1;
                else
                    keep = Mg[(size_t)qg0 * Sc + kv * KT + ct * 16 + hi4 * 4 + r] != 0;
                p[r] = keep ? exp2f(sc[ct][r]) * rls : 0.0f;
            }
            uint2 pp; pp.x = cvtpk(p[0], p[1]); pp.y = cvtpk(p[2], p[3]);
            *reinterpret_cast<uint2*>(
                lds + PS_OFF + swz(ql0, ct * 32 + hi4 * 8)) = pp;
        }
        // wave-local fence: Ps writes -> reads below (same wave's rows)
        fence_lgkm();

        // PV: oa += P(bf16) * V^T(bf16)
        #pragma unroll
        for (int kk = 0; kk < 2; ++kk) {
            int bc = kk * 64 + hi4 * 16;       // k = kk*32 + hi4*8 + e
            short8 a0 = ldlds(lds, PS_OFF, qw + l15, bc);
            #pragma unroll
            for (int dt = 0; dt < 4; ++dt) {
                short8 b = ldlds(lds, cvo, dt * 16 + l15, bc);
                oa[dt] = mfma16(a0, b, oa[dt]);
            }
        }

        // W flush, transposed, read from Ps: lane -> row qw + j*4 + hi4,
        // k = l15*4..+3 (bf16 bytecol = l15*8). Each store instr = 4 FULL
        // 256B contiguous line-aligned row segments, NONTEMPORAL (R12 win).
        #pragma unroll
        for (int j = 0; j < 4; ++j) {
            int row = qw + j * 4 + hi4;
            uint2 pw = *reinterpret_cast<const uint2*>(
                lds + PS_OFF + swz(row, l15 * 8));
            f32x4 wv;
            wv[0] = __uint_as_float(pw.x << 16);
            wv[1] = __uint_as_float(pw.x & 0xffff0000u);
            wv[2] = __uint_as_float(pw.y << 16);
            wv[3] = __uint_as_float(pw.y & 0xffff0000u);
            __builtin_nontemporal_store(
                wv, reinterpret_cast<f32x4*>(
                    Wb + (size_t)row * Sc + kv * KT + l15 * 4));
        }

        // write-late staging for next tile, then the LDS-only barrier
        if (pf) {
            if constexpr (MODE == 2) {
                const int ht = t & 127;
                char* d = (t < 128)
                    ? lds + KS_OFF + ((kv + 1) & 1) * 8192 + ht * 16
                    : lds + VS_OFF + ((kv + 1) & 1) * 8192 + ht * 16;
                *reinterpret_cast<u32x4*>(d) = s0;
                *reinterpret_cast<u32x4*>(d + 2048) = s1;
                *reinterpret_cast<u32x4*>(d + 4096) = s2;
                *reinterpret_cast<u32x4*>(d + 6144) = s3;
            } else {
                stk_g(lds, KS_OFF + ((kv + 1) & 1) * 8192, t, sreg);
                stv_g(lds, VS_OFF + ((kv + 1) & 1) * 8192, t, vreg);
            }
        }
        bar_lgkm();
    }

    // epilogue: store O (nontemporal, coalesced; once per kernel)
    #pragma unroll
    for (int dt = 0; dt < 4; ++dt)
        #pragma unroll
        for (int r = 0; r < 4; ++r) {
            int ql = qw + hi4 * 4 + r;
            __builtin_nontemporal_store(
                oa[dt][r], Ob + (size_t)ql * Dc + dt * 16 + l15);
        }
}

} // namespace

extern "C" void kernel_launch(void* const* d_in, const int* in_sizes, int n_in,
                              void* d_out, int out_size, void* d_ws, size_t ws_size,
                              hipStream_t stream) {
    const float* Qg = (const float*)d_in[0];
    const float* Kg = (const float*)d_in[1];
    const float* Vg = (const float*)d_in[2];
    const int*   Mg = (const int*)d_in[3];
    float* out_o = (float*)d_out;
    float* out_w = out_o + (size_t)Bc * Hc * Sc * Dc;   // weights after output

    char* ws = (char*)d_ws;
    dim3 grid(NQB * NBH), blk(256);

    if (d_ws != nullptr && ws_size >= WS_FULL) {
        unsigned long long* bits = (unsigned long long*)ws;
        char* kimg = ws + KIMG_OFF;
        char* vimg = ws + VIMG_OFF;
        pack_mask<<<(Sc * Sc) / 256, 256, 0, stream>>>(Mg, bits);
        pack_kv<<<NBH * NKV, 256, 0, stream>>>(Kg, Vg, kimg, vimg);
        attn_main<2><<<grid, blk, 0, stream>>>(
            Qg, Kg, Vg, Mg, (const unsigned*)bits, kimg, vimg, out_o, out_w);
    } else if (d_ws != nullptr && ws_size >= BITS_BYTES) {
        pack_mask<<<(Sc * Sc) / 256, 256, 0, stream>>>(
            Mg, (unsigned long long*)ws);
        attn_main<1><<<grid, blk, 0, stream>>>(
            Qg, Kg, Vg, Mg, (const unsigned*)ws, nullptr, nullptr, out_o, out_w);
    } else {
        attn_main<0><<<grid, blk, 0, stream>>>(
            Qg, Kg, Vg, Mg, nullptr, nullptr, nullptr, out_o, out_w);
    }
}